// Round 8
// baseline (405.079 us; speedup 1.0000x reference)
//
#include <hip/hip_runtime.h>

typedef unsigned short u16;
typedef __attribute__((ext_vector_type(8))) short short8;
typedef __attribute__((ext_vector_type(4))) float f32x4;

#define MFMA16 __builtin_amdgcn_mfma_f32_16x16x32_bf16

// ---- bf16 helpers (bit-level, RNE) ----------------------------------------
static __device__ __forceinline__ float bf2f(u16 u) {
  union { unsigned u; float f; } c; c.u = ((unsigned)u) << 16; return c.f;
}
static __device__ __forceinline__ u16 f2bf(float f) {
  union { float f; unsigned u; } c; c.f = f;
  return (u16)((c.u + 0x7fffu + ((c.u >> 16) & 1u)) >> 16);
}
static __device__ __forceinline__ void gload16(const u16* g, u16* l) {
  __builtin_amdgcn_global_load_lds(
      (const __attribute__((address_space(1))) unsigned int*)g,
      (__attribute__((address_space(3))) unsigned int*)l, 16, 0, 0);
}

// ---- x (f32) -> xb (bf16), 8 elems/thread ---------------------------------
__global__ __launch_bounds__(256) void cvt_x(const float* __restrict__ x,
                                             u16* __restrict__ xb) {
  const int i = (blockIdx.x * 256 + threadIdx.x) * 8;
  const float4 a = *(const float4*)(x + i);
  const float4 b = *(const float4*)(x + i + 4);
  short8 o;
  o[0] = (short)f2bf(a.x); o[1] = (short)f2bf(a.y);
  o[2] = (short)f2bf(a.z); o[3] = (short)f2bf(a.w);
  o[4] = (short)f2bf(b.x); o[5] = (short)f2bf(b.y);
  o[6] = (short)f2bf(b.z); o[7] = (short)f2bf(b.w);
  *(short8*)(xb + i) = o;
}

// ---- weight transpose + cvt: WT[n][k] = bf16(W[k][n]), 1024x1024 ----------
__global__ __launch_bounds__(256) void transpose_w(
    const float* __restrict__ Wq, const float* __restrict__ Wk,
    const float* __restrict__ Wv, const float* __restrict__ Wp,
    u16* __restrict__ wT) {
  __shared__ float tile[32][33];
  const float* src = blockIdx.z == 0 ? Wq : blockIdx.z == 1 ? Wk : blockIdx.z == 2 ? Wv : Wp;
  u16* dst = wT + (size_t)blockIdx.z * 1048576;
  const int tx = threadIdx.x, ty = threadIdx.y;
  const int x = blockIdx.x * 32 + tx;
#pragma unroll
  for (int i = 0; i < 32; i += 8)
    tile[ty + i][tx] = src[(size_t)(blockIdx.y * 32 + ty + i) * 1024 + x];
  __syncthreads();
  const int ox = blockIdx.y * 32 + tx;
#pragma unroll
  for (int i = 0; i < 32; i += 8)
    dst[(size_t)(blockIdx.x * 32 + ty + i) * 1024 + ox] = f2bf(tile[tx][ty + i]);
}

// ---- 128x128-tile bf16 GEMM, BT input ([N,K] row-major, bf16) -------------
// MODE 0: z in {0,1,2} -> Wq/Wk/Wv. Epilogue: q -> q_ws (bf16 [B,H,S,HD]);
//   K/V -> cached_kv f32 at outf+4194304 ([B,2,H,S,HD]); K -> kb_ws (bf16),
//   V -> vT_ws (bf16 [B,H,HD,S]).  MODE 1: y -> outf[0..] f32 [B,S,D].
template <int MODE>
__global__ __launch_bounds__(256) void gemm128(
    const u16* __restrict__ A, const u16* __restrict__ WTb,
    const float* __restrict__ bias_q, const float* __restrict__ bias_k,
    const float* __restrict__ bias_v,
    u16* __restrict__ q_ws, u16* __restrict__ kb_ws, u16* __restrict__ vT_ws,
    float* __restrict__ outf) {
  constexpr int K = 1024;
  const int z = (MODE == 0) ? blockIdx.z : 0;
  const u16* Bt = WTb + (size_t)z * 1048576;
  const float* bias = (MODE == 0) ? (z == 0 ? bias_q : z == 1 ? bias_k : bias_v) : bias_q;
  const int tn = blockIdx.x * 128, tm = blockIdx.y * 128;
  __shared__ __align__(16) u16 lA[128 * 32];
  __shared__ __align__(16) u16 lB[128 * 32];
  const int tid = threadIdx.x, w = tid >> 6, lane = tid & 63;
  const int wr = (w >> 1) * 64, wc = (w & 1) * 64;
  const int ar = lane & 15, ak = (lane >> 4) * 8;
  f32x4 acc[4][4] = {};
  for (int kt = 0; kt < K; kt += 32) {
#pragma unroll
    for (int i = 0; i < 2; ++i) {
      const int seg = i * 256 + w * 64 + lane;            // 16B segment id
      gload16(A + (size_t)(tm + (seg >> 2)) * K + kt + (seg & 3) * 8,
              lA + (size_t)(i * 256 + w * 64) * 8);       // wave-uniform base
      gload16(Bt + (size_t)(tn + (seg >> 2)) * K + kt + (seg & 3) * 8,
              lB + (size_t)(i * 256 + w * 64) * 8);
    }
    __syncthreads();
    short8 af[4], bf[4];
#pragma unroll
    for (int m = 0; m < 4; ++m) af[m] = *(const short8*)(lA + (wr + m * 16 + ar) * 32 + ak);
#pragma unroll
    for (int n = 0; n < 4; ++n) bf[n] = *(const short8*)(lB + (wc + n * 16 + ar) * 32 + ak);
#pragma unroll
    for (int m = 0; m < 4; ++m)
#pragma unroll
      for (int n = 0; n < 4; ++n) acc[m][n] = MFMA16(af[m], bf[n], acc[m][n], 0, 0, 0);
    __syncthreads();
  }
  // epilogue: C layout col = lane&15, row = (lane>>4)*4 + i
  const int r4 = (lane >> 4) * 4;
#pragma unroll
  for (int n = 0; n < 4; ++n) {
    const int ncol = tn + wc + n * 16 + ar;
    const float bv = bias[ncol];
#pragma unroll
    for (int m = 0; m < 4; ++m) {
      const int mr = tm + wr + m * 16 + r4;
#pragma unroll
      for (int i = 0; i < 4; ++i) {
        const float val = acc[m][n][i] + bv;
        const int row = mr + i;
        if (MODE == 1) {
          outf[(size_t)row * 1024 + ncol] = val;          // y [B,S,D] f32
        } else {
          const int b = row >> 11, s = row & 2047;
          const int hh = ncol >> 6, hd = ncol & 63;
          if (z == 0) {
            q_ws[(((size_t)(b * 16 + hh)) * 2048 + s) * 64 + hd] = f2bf(val);
          } else {
            // cached_kv [B,2,H,S,HD] f32 at element offset 4194304 of d_out
            outf[4194304u + ((((size_t)b * 2 + (z - 1)) * 16 + hh) * 2048 + s) * 64 + hd] = val;
            if (z == 1)
              kb_ws[(((size_t)(b * 16 + hh)) * 2048 + s) * 64 + hd] = f2bf(val);
            else
              vT_ws[(((size_t)(b * 16 + hh)) * 64 + hd) * 2048 + s] = f2bf(val);  // V^T
          }
        }
      }
    }
  }
}

// ---- causal flash attention: 4 waves/block, 16 q-rows per wave ------------
__global__ __launch_bounds__(256) void attn_kernel(
    const u16* __restrict__ q_ws, const u16* __restrict__ kb_ws,
    const u16* __restrict__ vT_ws, u16* __restrict__ y_attn) {
  const int bh = blockIdx.y, b = bh >> 4, h = bh & 15;
  const int w = threadIdx.x >> 6, lane = threadIdx.x & 63;
  const int ar = lane & 15, ag = lane >> 4;
  const int qb = blockIdx.x * 64 + w * 16;
  const u16* Qp = q_ws + (size_t)bh * 2048 * 64;
  const u16* Kp = kb_ws + (size_t)bh * 2048 * 64;
  const u16* Vt = vT_ws + (size_t)bh * 64 * 2048;
  __shared__ __align__(16) u16 p_lds[4][16][32];

  // Q fragments, pre-scaled by 1/sqrt(64) = 2^-3 (exact in bf16)
  short8 qf[2];
#pragma unroll
  for (int kk = 0; kk < 2; ++kk) {
    short8 t = *(const short8*)(Qp + (size_t)(qb + ar) * 64 + kk * 32 + ag * 8);
#pragma unroll
    for (int j = 0; j < 8; ++j) t[j] = (short)f2bf(bf2f((u16)t[j]) * 0.125f);
    qf[kk] = t;
  }
  f32x4 acc[4] = {};
  float m_run[4], l_run[4];
#pragma unroll
  for (int i = 0; i < 4; ++i) { m_run[i] = -1e30f; l_run[i] = 0.f; }
  const int q_hi = qb + 15;
  for (int kt = 0; kt <= q_hi; kt += 32) {
    const short8 kf00 = *(const short8*)(Kp + (size_t)(kt + ar) * 64 + ag * 8);
    const short8 kf01 = *(const short8*)(Kp + (size_t)(kt + ar) * 64 + 32 + ag * 8);
    const short8 kf10 = *(const short8*)(Kp + (size_t)(kt + 16 + ar) * 64 + ag * 8);
    const short8 kf11 = *(const short8*)(Kp + (size_t)(kt + 16 + ar) * 64 + 32 + ag * 8);
    const f32x4 zz = {0.f, 0.f, 0.f, 0.f};
    f32x4 s0 = MFMA16(qf[0], kf00, zz, 0, 0, 0);
    s0 = MFMA16(qf[1], kf01, s0, 0, 0, 0);
    f32x4 s1 = MFMA16(qf[0], kf10, zz, 0, 0, 0);
    s1 = MFMA16(qf[1], kf11, s1, 0, 0, 0);
    // clamp (NaN/inf-proof) then causal mask
#pragma unroll
    for (int i = 0; i < 4; ++i) {
      s0[i] = fminf(fmaxf(s0[i], -1e30f), 1e30f);
      s1[i] = fminf(fmaxf(s1[i], -1e30f), 1e30f);
      const int row = qb + ag * 4 + i;
      if (kt + ar > row) s0[i] = -1e30f;
      if (kt + 16 + ar > row) s1[i] = -1e30f;
    }
    float mt[4], st[4], corr[4];
#pragma unroll
    for (int i = 0; i < 4; ++i) mt[i] = fmaxf(s0[i], s1[i]);
#pragma unroll
    for (int off = 1; off < 16; off <<= 1)
#pragma unroll
      for (int i = 0; i < 4; ++i) mt[i] = fmaxf(mt[i], __shfl_xor(mt[i], off, 64));
#pragma unroll
    for (int i = 0; i < 4; ++i) {
      const float mn = fmaxf(m_run[i], mt[i]);
      corr[i] = __expf(m_run[i] - mn);
      m_run[i] = mn;
      s0[i] = __expf(s0[i] - mn);
      s1[i] = __expf(s1[i] - mn);
      st[i] = s0[i] + s1[i];
    }
#pragma unroll
    for (int off = 1; off < 16; off <<= 1)
#pragma unroll
      for (int i = 0; i < 4; ++i) st[i] += __shfl_xor(st[i], off, 64);
#pragma unroll
    for (int i = 0; i < 4; ++i) l_run[i] = l_run[i] * corr[i] + st[i];
#pragma unroll
    for (int oc = 0; oc < 4; ++oc)
#pragma unroll
      for (int i = 0; i < 4; ++i) acc[oc][i] *= corr[i];
    // P: C-layout -> A-layout via per-wave LDS round-trip
#pragma unroll
    for (int i = 0; i < 4; ++i) {
      p_lds[w][ag * 4 + i][ar] = f2bf(s0[i]);
      p_lds[w][ag * 4 + i][16 + ar] = f2bf(s1[i]);
    }
    __builtin_amdgcn_sched_barrier(0);
    asm volatile("s_waitcnt lgkmcnt(0)" ::: "memory");
    __builtin_amdgcn_sched_barrier(0);
    const short8 pf = *(const short8*)(&p_lds[w][ar][ag * 8]);
#pragma unroll
    for (int oc = 0; oc < 4; ++oc) {
      const short8 vf = *(const short8*)(Vt + (size_t)(oc * 16 + ar) * 2048 + kt + ag * 8);
      acc[oc] = MFMA16(pf, vf, acc[oc], 0, 0, 0);
    }
  }
#pragma unroll
  for (int oc = 0; oc < 4; ++oc)
#pragma unroll
    for (int i = 0; i < 4; ++i) {
      const int row = qb + ag * 4 + i;
      const int col = h * 64 + oc * 16 + ar;
      const float inv_l = 1.0f / fmaxf(l_run[i], 1e-30f);
      y_attn[((size_t)(b * 2048 + row)) * 1024 + col] = f2bf(acc[oc][i] * inv_l);
    }
}

extern "C" void kernel_launch(void* const* d_in, const int* in_sizes, int n_in,
                              void* d_out, int out_size, void* d_ws, size_t ws_size,
                              hipStream_t stream) {
  // Inputs f32 (reference dtypes), output f32; bf16 only internally.
  const float* x  = (const float*)d_in[0];
  const float* Wq = (const float*)d_in[1];
  const float* bq = (const float*)d_in[2];
  const float* Wk = (const float*)d_in[3];
  const float* bk = (const float*)d_in[4];
  const float* Wv = (const float*)d_in[5];
  const float* bv = (const float*)d_in[6];
  const float* Wp = (const float*)d_in[7];
  const float* bp = (const float*)d_in[8];
  float* outf = (float*)d_out;

  // ws (bf16 elems): wT(4M) | kb(4M) | vT(4M) | yat(4M) = 32 MB
  u16* wT  = (u16*)d_ws;
  u16* kb  = wT + (size_t)4 * 1048576;
  u16* vT  = kb + (size_t)4194304;
  u16* yat = vT + (size_t)4194304;
  // xb and q live in d_out's y region (16.78 MB f32, dead until final GEMM):
  //   xb at u16 elems [0, 4.19M), q at [4.19M, 8.39M)
  u16* xb   = (u16*)outf;
  u16* qbuf = xb + (size_t)4194304;

  cvt_x<<<2048, 256, 0, stream>>>(x, xb);
  transpose_w<<<dim3(32, 32, 4), dim3(32, 8), 0, stream>>>(Wq, Wk, Wv, Wp, wT);
  gemm128<0><<<dim3(8, 32, 3), 256, 0, stream>>>(xb, wT, bq, bk, bv,
                                                 qbuf, kb, vT, outf);
  attn_kernel<<<dim3(32, 32), 256, 0, stream>>>(qbuf, kb, vT, yat);
  gemm128<1><<<dim3(8, 32, 1), 256, 0, stream>>>(yat, wT + (size_t)3 * 1048576,
                                                 bp, bp, bp, qbuf, kb, vT, outf);
}